// Round 12
// baseline (256.716 us; speedup 1.0000x reference)
//
#include <hip/hip_runtime.h>
#include <hip/hip_bf16.h>

#define NN 10000     // nodes
#define NE 640000    // edges
#define NG 64        // graphs
#define NF 128       // feature dim (both layers)
#define NC 10        // classes
#define TM 32        // gemm row tile
#define TKC 32       // gemm k chunk
#define NB 250       // dst buckets (40 nodes each)
#define BSZ 40       // nodes per bucket
#define G1 512       // blocks in hist/bucket passes (2 blocks/CU)
#define ECHUNK 1250  // edges per block (G1*ECHUNK == NE)
#define SORTN 4096   // bitonic size (max bucket ~2800 edges, pad sentinel)

// ---------------- ws layout (bytes) ----------------
// 0        coff  (10001 int)     40016
// 40016    bbase (251 int)       1024
// 41040    btot  (250 int)       1024
// 42064    dinv  (10000 f32)     40000
// 82064    csrc  (640000 int)    2560000
// 2642064  bufA  (10000*128 f32) 5120000  [bh (512KB) aliases head: dead before gemm1]
// 7762064  bufB  (10000*128 f32) 5120000  [ebuf (2.56MB) aliases head: dead before gath1]
// total ~12.9 MB; zero global atomics -> no pre-zeroing needed
//
// Math: GCN layer out[i] = relu( dinv[i]*(sum_{j->i} g[j] + g[i]) + b ),
// g = dinv*h folded into the GEMM epilogue -> weight-free gather.
// csrc is sorted by src WITHIN each dst (R12): concurrent gather waves sweep
// src-space together, so the hot slice of G stays L2-resident (latency lever).

// Wave-uniform detection of int64 vs int32 index buffers. For little-endian
// int64, every odd 32-bit word is the (always-zero here) high half.
__device__ __forceinline__ int detect64(const int* w, long span) {
    int lane = threadIdx.x & 63;
    long e = (long)lane * (span - 1) / 63;
    return (__ballot(w[2 * e + 1] != 0) == 0ULL) ? 1 : 0;
}

__device__ __forceinline__ int ld_idx(const void* p, long i, int is64) {
    return is64 ? (int)((const long long*)p)[i] : ((const int*)p)[i];
}

// Pass A: per-block bucket histogram, stored bucket-major: bh[b*G1 + g].
__global__ __launch_bounds__(256) void k_hist(const void* __restrict__ ei,
                                              int* __restrict__ bh) {
    int is64 = detect64((const int*)ei, NE);
    __shared__ int hist[256];
    int tid = threadIdx.x;
    hist[tid] = 0;
    __syncthreads();
    int e0 = blockIdx.x * ECHUNK, e1 = min(NE, e0 + ECHUNK);
    for (int e = e0 + tid; e < e1; e += 256) {
        int dst = ld_idx(ei, (long)NE + e, is64);
        atomicAdd(&hist[dst / BSZ], 1);
    }
    __syncthreads();
    bh[tid * G1 + blockIdx.x] = hist[tid];
}

// Pass B1: per-bucket exclusive prefix over the G1 group counts, parallel
// across 63 blocks (one wave per bucket; 8 vals/lane + shfl wave scan).
__global__ __launch_bounds__(256) void k_bscan1(int* __restrict__ bh,
                                                int* __restrict__ btot) {
    int w = blockIdx.x * 4 + (threadIdx.x >> 6);
    if (w >= NB) return;
    int lane = threadIdx.x & 63;
    int base = w * G1 + lane * 8;
    int vals[8];
    int lsum = 0;
#pragma unroll
    for (int i = 0; i < 8; ++i) { vals[i] = bh[base + i]; lsum += vals[i]; }
    int pref = lsum;
    for (int o = 1; o < 64; o <<= 1) {
        int t = __shfl_up(pref, o, 64);
        if (lane >= o) pref += t;
    }
    int run = pref - lsum;                  // exclusive
#pragma unroll
    for (int i = 0; i < 8; ++i) { int v = vals[i]; bh[base + i] = run; run += v; }
    if (lane == 63) btot[w] = run;
}

// Pass B2: scan 250 bucket totals -> bbase (tiny).
__global__ __launch_bounds__(256) void k_bscan2(const int* __restrict__ btot,
                                                int* __restrict__ bbase) {
    __shared__ int s[256];
    int tid = threadIdx.x;
    s[tid] = (tid < NB) ? btot[tid] : 0;
    __syncthreads();
    if (tid == 0) {
        int run = 0;
        for (int b = 0; b < NB; ++b) { int v = s[b]; s[b] = run; run += v; }
    }
    __syncthreads();
    if (tid < NB) bbase[tid] = s[tid];
    if (tid == 0) bbase[NB] = NE;
}

// Pass C: scatter edges to bucket regions, packed (ldst<<14)|src. Each block
// owns a CONTIGUOUS sub-range per bucket (prefix cursors) -> low write amp.
__global__ __launch_bounds__(256) void k_bucket(const void* __restrict__ ei,
                                                const int* __restrict__ bh,
                                                const int* __restrict__ bbase,
                                                int* __restrict__ ebuf) {
    int is64 = detect64((const int*)ei, NE);
    __shared__ int cur[256];
    int tid = threadIdx.x;
    if (tid < NB) cur[tid] = bh[tid * G1 + blockIdx.x] + bbase[tid];
    __syncthreads();
    int e0 = blockIdx.x * ECHUNK, e1 = min(NE, e0 + ECHUNK);
    for (int e = e0 + tid; e < e1; e += 256) {
        int dst = ld_idx(ei, (long)NE + e, is64);
        int src = ld_idx(ei, (long)e, is64);
        int b = dst / BSZ;
        int p = atomicAdd(&cur[b], 1);
        ebuf[p] = ((dst - b * BSZ) << 14) | src;
    }
}

// Pass D: one block per bucket. LDS bitonic sort of packed keys -> edges
// grouped by dst AND src-ascending within dst (gather L2-window locality).
// Sorted order makes the csrc write sequential (no scatter). Also coff/dinv.
__global__ __launch_bounds__(256) void k_csr(const int* __restrict__ ebuf,
                                             const int* __restrict__ bbase,
                                             int* __restrict__ coff,
                                             float* __restrict__ dinv,
                                             int* __restrict__ csrc) {
    __shared__ int s[SORTN];             // 16 KB
    __shared__ int dcount[BSZ];
    __shared__ int dstart[BSZ];
    int b = blockIdx.x, tid = threadIdx.x;
    int base = bbase[b], end = bbase[b + 1];
    int cnt = end - base;
    for (int i = tid; i < SORTN; i += 256)
        s[i] = (i < cnt) ? ebuf[base + i] : 0x7FFFFFFF;
    if (tid < BSZ) dcount[tid] = 0;
    __syncthreads();
    for (int i = tid; i < cnt; i += 256)
        atomicAdd(&dcount[s[i] >> 14], 1);
    // bitonic sort (ascending): key = (ldst<<14)|src
    for (int k = 2; k <= SORTN; k <<= 1) {
        for (int j = k >> 1; j > 0; j >>= 1) {
            __syncthreads();
            for (int t = tid; t < SORTN / 2; t += 256) {
                int i = ((t & ~(j - 1)) << 1) | (t & (j - 1));
                int p = i | j;
                int a = s[i], c = s[p];
                bool up = ((i & k) == 0);
                if ((a > c) == up) { s[i] = c; s[p] = a; }
            }
        }
    }
    __syncthreads();
    if (tid == 0) {
        int run = 0;
        for (int i = 0; i < BSZ; ++i) { dstart[i] = run; run += dcount[i]; }
    }
    __syncthreads();
    if (tid < BSZ) {
        coff[b * BSZ + tid] = base + dstart[tid];
        dinv[b * BSZ + tid] = rsqrtf((float)dcount[tid] + 1.0f);
    }
    if (b == NB - 1 && tid == 0) coff[NN] = NE;
    for (int i = tid; i < cnt; i += 256)
        csrc[base + i] = s[i] & 16383;
}

// Y = (X @ W) * dinv[row], register-tiled. Block: 256 thr, 32 rows x 128 cols;
// 4x4 acc. The dinv row-scale in the epilogue makes the gather weight-free.
__global__ __launch_bounds__(256) void k_gemm(const float* __restrict__ X,
                                              const float* __restrict__ W,
                                              const float* __restrict__ dinv,
                                              float* __restrict__ Y, int nrows) {
    __shared__ float sX[TKC * 36];       // 4.6 KB
    __shared__ float sW[32 * 132];       // 16.9 KB
    int tid = threadIdx.x;
    int rg = tid & 7;                    // rows rg*4 .. rg*4+3
    int cg = tid >> 3;                   // cols cg*4 .. cg*4+3 (0..31)
    int m0 = blockIdx.x * TM;
    float acc[4][4] = {{0.f}};
    for (int kc = 0; kc < NF / TKC; ++kc) {
        int k0 = kc * TKC;
        {   // stage X^T (one float4 per thread)
            int row = tid >> 3, kq = tid & 7;
            int mm = m0 + row; if (mm > nrows - 1) mm = nrows - 1;
            float4 v = *(const float4*)(X + (size_t)mm * NF + k0 + kq * 4);
            sX[(kq * 4 + 0) * 36 + row] = v.x;
            sX[(kq * 4 + 1) * 36 + row] = v.y;
            sX[(kq * 4 + 2) * 36 + row] = v.z;
            sX[(kq * 4 + 3) * 36 + row] = v.w;
        }
#pragma unroll
        for (int j = 0; j < 4; ++j) {    // stage W panels (4 float4 per thread)
            int idx = tid + 256 * j;
            int k = idx >> 5, cq = idx & 31;
            float4 v = *(const float4*)(W + (size_t)(k0 + k) * NF + cq * 4);
            *(float4*)(sW + cq * 132 + k * 4) = v;
        }
        __syncthreads();
#pragma unroll 8
        for (int k = 0; k < TKC; ++k) {
            float4 xf = *(const float4*)(sX + k * 36 + rg * 4);
            float4 wf = *(const float4*)(sW + cg * 132 + k * 4);
            acc[0][0] = fmaf(xf.x, wf.x, acc[0][0]);
            acc[0][1] = fmaf(xf.x, wf.y, acc[0][1]);
            acc[0][2] = fmaf(xf.x, wf.z, acc[0][2]);
            acc[0][3] = fmaf(xf.x, wf.w, acc[0][3]);
            acc[1][0] = fmaf(xf.y, wf.x, acc[1][0]);
            acc[1][1] = fmaf(xf.y, wf.y, acc[1][1]);
            acc[1][2] = fmaf(xf.y, wf.z, acc[1][2]);
            acc[1][3] = fmaf(xf.y, wf.w, acc[1][3]);
            acc[2][0] = fmaf(xf.z, wf.x, acc[2][0]);
            acc[2][1] = fmaf(xf.z, wf.y, acc[2][1]);
            acc[2][2] = fmaf(xf.z, wf.z, acc[2][2]);
            acc[2][3] = fmaf(xf.z, wf.w, acc[2][3]);
            acc[3][0] = fmaf(xf.w, wf.x, acc[3][0]);
            acc[3][1] = fmaf(xf.w, wf.y, acc[3][1]);
            acc[3][2] = fmaf(xf.w, wf.z, acc[3][2]);
            acc[3][3] = fmaf(xf.w, wf.w, acc[3][3]);
        }
        __syncthreads();
    }
#pragma unroll
    for (int r = 0; r < 4; ++r) {
        int m = m0 + rg * 4 + r;
        if (m < nrows) {
            float ds = dinv[m];
            *(float4*)(Y + (size_t)m * NF + cg * 4) =
                make_float4(acc[r][0] * ds, acc[r][1] * ds,
                            acc[r][2] * ds, acc[r][3] * ds);
        }
    }
}

// OUT[n] = relu( dinv[n]*( sum_e G[csrc[e]] + G[n] ) + bias ), G pre-scaled.
// One wave per node; half-wave (32 lanes x float4 = 512B) per edge; 4-deep
// unroll -> 8 independent row reads in flight per wave. csrc now src-sorted
// per node -> concurrent waves share a moving L2-resident window of G.
__global__ __launch_bounds__(256) void k_gather(const float* __restrict__ G,
                                                const int* __restrict__ off,
                                                const int* __restrict__ csrc,
                                                const float* __restrict__ dinv,
                                                const float* __restrict__ bias,
                                                float* __restrict__ OUT) {
    int wid = threadIdx.x >> 6, lane = threadIdx.x & 63;
    int half = lane >> 5;
    int c4 = lane & 31;
    int n = blockIdx.x * 4 + wid;
    if (n >= NN) return;
    int beg = off[n], end = off[n + 1];
    float din = dinv[n];
    float4 acc = make_float4(0.f, 0.f, 0.f, 0.f);
    int e = beg + half;
    for (; e + 6 < end; e += 8) {
        int s0 = csrc[e];
        int s1 = csrc[e + 2];
        int s2 = csrc[e + 4];
        int s3 = csrc[e + 6];
        float4 v0 = ((const float4*)(G + (size_t)s0 * NF))[c4];
        float4 v1 = ((const float4*)(G + (size_t)s1 * NF))[c4];
        float4 v2 = ((const float4*)(G + (size_t)s2 * NF))[c4];
        float4 v3 = ((const float4*)(G + (size_t)s3 * NF))[c4];
        acc.x += v0.x; acc.y += v0.y; acc.z += v0.z; acc.w += v0.w;
        acc.x += v1.x; acc.y += v1.y; acc.z += v1.z; acc.w += v1.w;
        acc.x += v2.x; acc.y += v2.y; acc.z += v2.z; acc.w += v2.w;
        acc.x += v3.x; acc.y += v3.y; acc.z += v3.z; acc.w += v3.w;
    }
    for (; e < end; e += 2) {
        int s = csrc[e];
        float4 v = ((const float4*)(G + (size_t)s * NF))[c4];
        acc.x += v.x; acc.y += v.y; acc.z += v.z; acc.w += v.w;
    }
    acc.x += __shfl_xor(acc.x, 32);
    acc.y += __shfl_xor(acc.y, 32);
    acc.z += __shfl_xor(acc.z, 32);
    acc.w += __shfl_xor(acc.w, 32);
    if (half == 0) {
        float4 sv = ((const float4*)(G + (size_t)n * NF))[c4];
        float4 bb = ((const float4*)bias)[c4];
        float4 o;
        o.x = fmaxf(fmaf(din, acc.x + sv.x, bb.x), 0.f);
        o.y = fmaxf(fmaf(din, acc.y + sv.y, bb.y), 0.f);
        o.z = fmaxf(fmaf(din, acc.z + sv.z, bb.z), 0.f);
        o.w = fmaxf(fmaf(din, acc.w + sv.w, bb.w), 0.f);
        ((float4*)(OUT + (size_t)n * NF))[c4] = o;
    }
}

// Fused global-mean-pool + final linear (batch is sorted -> contiguous ranges).
__global__ __launch_bounds__(256) void k_poolfin(const float* __restrict__ H,
                                                 const void* __restrict__ batch,
                                                 const float* __restrict__ Wl,
                                                 const float* __restrict__ bl,
                                                 float* __restrict__ out) {
    int is64 = detect64((const int*)batch, NN / 2);
    __shared__ int sb[2];
    __shared__ float4 part[256];
    __shared__ float pooled[NF];
    int g = blockIdx.x;
    int tid = threadIdx.x;
    if (tid < 2) {
        int target = g + tid;                 // lower_bound(batch, target)
        int lo = 0, hi = NN;
        while (lo < hi) {
            int mid = (lo + hi) >> 1;
            if (ld_idx(batch, mid, is64) < target) lo = mid + 1; else hi = mid;
        }
        sb[tid] = lo;
    }
    __syncthreads();
    int beg = sb[0], end = sb[1];
    int c4 = tid & 31, r = tid >> 5;          // 8 rows in flight
    float4 acc = make_float4(0.f, 0.f, 0.f, 0.f);
    for (int n = beg + r; n < end; n += 8) {
        float4 v = ((const float4*)(H + (size_t)n * NF))[c4];
        acc.x += v.x; acc.y += v.y; acc.z += v.z; acc.w += v.w;
    }
    part[tid] = acc;
    __syncthreads();
    if (tid < 32) {
        float4 s = part[tid];
#pragma unroll
        for (int j = 1; j < 8; j++) {
            float4 p = part[tid + 32 * j];
            s.x += p.x; s.y += p.y; s.z += p.z; s.w += p.w;
        }
        float ic = 1.0f / fmaxf((float)(end - beg), 1.0f);
        pooled[tid * 4 + 0] = s.x * ic;
        pooled[tid * 4 + 1] = s.y * ic;
        pooled[tid * 4 + 2] = s.z * ic;
        pooled[tid * 4 + 3] = s.w * ic;
    }
    __syncthreads();
    if (tid < NC) {
        float a = bl[tid];
#pragma unroll 8
        for (int k = 0; k < NF; k++)
            a = fmaf(pooled[k], Wl[k * NC + tid], a);
        out[g * NC + tid] = a;
    }
}

extern "C" void kernel_launch(void* const* d_in, const int* in_sizes, int n_in,
                              void* d_out, int out_size, void* d_ws, size_t ws_size,
                              hipStream_t stream) {
    const float* x  = (const float*)d_in[0];
    const void*  ei = d_in[1];
    const void*  bt = d_in[2];
    const float* W1 = (const float*)d_in[3];
    const float* b1 = (const float*)d_in[4];
    const float* W2 = (const float*)d_in[5];
    const float* b2 = (const float*)d_in[6];
    const float* Wl = (const float*)d_in[7];
    const float* bl = (const float*)d_in[8];

    char* ws = (char*)d_ws;
    int*   coff  = (int*)(ws + 0);
    int*   bbase = (int*)(ws + 40016);
    int*   btot  = (int*)(ws + 41040);
    float* dinv  = (float*)(ws + 42064);
    int*   csrc  = (int*)(ws + 82064);
    float* bufA  = (float*)(ws + 2642064);
    float* bufB  = (float*)(ws + 7762064);
    int*   bh    = (int*)bufA;     // 512 KB scratch, dead before k_gemm #1
    int*   ebuf  = (int*)bufB;     // 2.56 MB scratch, dead before k_gather #1

    k_hist  <<<G1, 256, 0, stream>>>(ei, bh);
    k_bscan1<<<(NB + 3) / 4, 256, 0, stream>>>(bh, btot);
    k_bscan2<<<1, 256, 0, stream>>>(btot, bbase);
    k_bucket<<<G1, 256, 0, stream>>>(ei, bh, bbase, ebuf);
    k_csr   <<<NB, 256, 0, stream>>>(ebuf, bbase, coff, dinv, csrc);

    k_gemm<<<(NN + TM - 1) / TM, 256, 0, stream>>>(x, W1, dinv, bufA, NN);
    k_gather<<<(NN + 3) / 4, 256, 0, stream>>>(bufA, coff, csrc, dinv, b1, bufB);
    k_gemm<<<(NN + TM - 1) / TM, 256, 0, stream>>>(bufB, W2, dinv, bufA, NN);
    k_gather<<<(NN + 3) / 4, 256, 0, stream>>>(bufA, coff, csrc, dinv, b2, bufB);

    k_poolfin<<<NG, 256, 0, stream>>>(bufB, bt, Wl, bl, (float*)d_out);
}

// Round 13
// 175.654 us; speedup vs baseline: 1.4615x; 1.4615x over previous
//
#include <hip/hip_runtime.h>
#include <hip/hip_bf16.h>

#define NN 10000     // nodes
#define NE 640000    // edges
#define NG 64        // graphs
#define NF 128       // feature dim (both layers)
#define NC 10        // classes
#define TM 32        // gemm row tile
#define TKC 32       // gemm k chunk
#define NB 250       // dst buckets (40 nodes each)
#define BSZ 40       // nodes per bucket
#define G1 512       // blocks in hist/bucket passes (2 blocks/CU)
#define ECHUNK 1250  // edges per block (G1*ECHUNK == NE)

// ---------------- ws layout (bytes) ----------------
// 0        coff  (10001 int)     40016
// 40016    bbase (251 int)       1024
// 41040    btot  (250 int)       1024
// 42064    dinv  (10000 f32)     40000
// 82064    csrc  (640000 int)    2560000
// 2642064  bufA  (G: 10000*128 bf16 = 2.56MB; also H-capable) 5120000
//          [bh (512KB) aliases head: dead before gemm1]
// 7762064  bufB  (10000*128 f32) 5120000
//          [ebuf (2.56MB) aliases head: dead before gather1 writes]
// total ~12.9 MB; zero global atomics -> no pre-zeroing needed
//
// Math: out[i] = relu( dinv[i]*(sum_{j->i} g[j] + g[i]) + b ), g = dinv*h
// folded into the GEMM epilogue. R13: G stored in bf16 (row = 256B = 4 cache
// lines/edge vs 8) -- halves the gather's line count, which R12 showed is
// the binding resource. All accumulation stays fp32.

__device__ __forceinline__ unsigned short f2bf(float f) {   // RNE
    unsigned int u = __float_as_uint(f);
    return (unsigned short)((u + 0x7FFF + ((u >> 16) & 1)) >> 16);
}
__device__ __forceinline__ float bf_lo(unsigned int p) {    // low bf16 of pair
    return __uint_as_float(p << 16);
}
__device__ __forceinline__ float bf_hi(unsigned int p) {    // high bf16 of pair
    return __uint_as_float(p & 0xFFFF0000u);
}

// Wave-uniform detection of int64 vs int32 index buffers. For little-endian
// int64, every odd 32-bit word is the (always-zero here) high half.
__device__ __forceinline__ int detect64(const int* w, long span) {
    int lane = threadIdx.x & 63;
    long e = (long)lane * (span - 1) / 63;
    return (__ballot(w[2 * e + 1] != 0) == 0ULL) ? 1 : 0;
}

__device__ __forceinline__ int ld_idx(const void* p, long i, int is64) {
    return is64 ? (int)((const long long*)p)[i] : ((const int*)p)[i];
}

// Pass A: per-block bucket histogram, stored bucket-major: bh[b*G1 + g].
__global__ __launch_bounds__(256) void k_hist(const void* __restrict__ ei,
                                              int* __restrict__ bh) {
    int is64 = detect64((const int*)ei, NE);
    __shared__ int hist[256];
    int tid = threadIdx.x;
    hist[tid] = 0;
    __syncthreads();
    int e0 = blockIdx.x * ECHUNK, e1 = min(NE, e0 + ECHUNK);
    for (int e = e0 + tid; e < e1; e += 256) {
        int dst = ld_idx(ei, (long)NE + e, is64);
        atomicAdd(&hist[dst / BSZ], 1);
    }
    __syncthreads();
    bh[tid * G1 + blockIdx.x] = hist[tid];
}

// Pass B1: per-bucket exclusive prefix over the G1 group counts, parallel
// across 63 blocks (one wave per bucket; 8 vals/lane + shfl wave scan).
__global__ __launch_bounds__(256) void k_bscan1(int* __restrict__ bh,
                                                int* __restrict__ btot) {
    int w = blockIdx.x * 4 + (threadIdx.x >> 6);
    if (w >= NB) return;
    int lane = threadIdx.x & 63;
    int base = w * G1 + lane * 8;
    int vals[8];
    int lsum = 0;
#pragma unroll
    for (int i = 0; i < 8; ++i) { vals[i] = bh[base + i]; lsum += vals[i]; }
    int pref = lsum;
    for (int o = 1; o < 64; o <<= 1) {
        int t = __shfl_up(pref, o, 64);
        if (lane >= o) pref += t;
    }
    int run = pref - lsum;                  // exclusive
#pragma unroll
    for (int i = 0; i < 8; ++i) { int v = vals[i]; bh[base + i] = run; run += v; }
    if (lane == 63) btot[w] = run;
}

// Pass B2: scan 250 bucket totals -> bbase (tiny).
__global__ __launch_bounds__(256) void k_bscan2(const int* __restrict__ btot,
                                                int* __restrict__ bbase) {
    __shared__ int s[256];
    int tid = threadIdx.x;
    s[tid] = (tid < NB) ? btot[tid] : 0;
    __syncthreads();
    if (tid == 0) {
        int run = 0;
        for (int b = 0; b < NB; ++b) { int v = s[b]; s[b] = run; run += v; }
    }
    __syncthreads();
    if (tid < NB) bbase[tid] = s[tid];
    if (tid == 0) bbase[NB] = NE;
}

// Pass C: scatter edges to bucket regions, packed (ldst<<14)|src. Each block
// owns a CONTIGUOUS sub-range per bucket (prefix cursors) -> low write amp.
__global__ __launch_bounds__(256) void k_bucket(const void* __restrict__ ei,
                                                const int* __restrict__ bh,
                                                const int* __restrict__ bbase,
                                                int* __restrict__ ebuf) {
    int is64 = detect64((const int*)ei, NE);
    __shared__ int cur[256];
    int tid = threadIdx.x;
    if (tid < NB) cur[tid] = bh[tid * G1 + blockIdx.x] + bbase[tid];
    __syncthreads();
    int e0 = blockIdx.x * ECHUNK, e1 = min(NE, e0 + ECHUNK);
    for (int e = e0 + tid; e < e1; e += 256) {
        int dst = ld_idx(ei, (long)NE + e, is64);
        int src = ld_idx(ei, (long)e, is64);
        int b = dst / BSZ;
        int p = atomicAdd(&cur[b], 1);
        ebuf[p] = ((dst - b * BSZ) << 14) | src;
    }
}

// Pass D: one block per bucket. Count/scan 40 dsts -> coff + dinv; scatter
// csrc within the block-private contiguous region. (R11 version; R12's LDS
// bitonic sort cost 79us for a ~10us gather gain -- removed.)
__global__ __launch_bounds__(256) void k_csr(const int* __restrict__ ebuf,
                                             const int* __restrict__ bbase,
                                             int* __restrict__ coff,
                                             float* __restrict__ dinv,
                                             int* __restrict__ csrc) {
    __shared__ int dcount[BSZ];
    __shared__ int dstart[BSZ];
    __shared__ int cur[BSZ];
    int b = blockIdx.x, tid = threadIdx.x;
    if (tid < BSZ) dcount[tid] = 0;
    __syncthreads();
    int base = bbase[b], end = bbase[b + 1];
    for (int i = base + tid; i < end; i += 256)
        atomicAdd(&dcount[ebuf[i] >> 14], 1);
    __syncthreads();
    if (tid == 0) {
        int run = 0;
        for (int i = 0; i < BSZ; ++i) {
            dstart[i] = run; cur[i] = base + run; run += dcount[i];
        }
    }
    __syncthreads();
    if (tid < BSZ) {
        coff[b * BSZ + tid] = base + dstart[tid];
        dinv[b * BSZ + tid] = rsqrtf((float)dcount[tid] + 1.0f);
    }
    if (b == NB - 1 && tid == 0) coff[NN] = NE;
    __syncthreads();
    for (int i = base + tid; i < end; i += 256) {
        int pk = ebuf[i];
        int p = atomicAdd(&cur[pk >> 14], 1);
        csrc[p] = pk & 16383;
    }
}

// Y(bf16) = (X @ W) * dinv[row]. Block: 256 thr, 32 rows x 128 cols; 4x4 acc.
// fp32 accumulate; RNE-rounded bf16 store (8B per thread per row).
__global__ __launch_bounds__(256) void k_gemm(const float* __restrict__ X,
                                              const float* __restrict__ W,
                                              const float* __restrict__ dinv,
                                              unsigned short* __restrict__ Y,
                                              int nrows) {
    __shared__ float sX[TKC * 36];       // 4.6 KB
    __shared__ float sW[32 * 132];       // 16.9 KB
    int tid = threadIdx.x;
    int rg = tid & 7;                    // rows rg*4 .. rg*4+3
    int cg = tid >> 3;                   // cols cg*4 .. cg*4+3 (0..31)
    int m0 = blockIdx.x * TM;
    float acc[4][4] = {{0.f}};
    for (int kc = 0; kc < NF / TKC; ++kc) {
        int k0 = kc * TKC;
        {   // stage X^T (one float4 per thread)
            int row = tid >> 3, kq = tid & 7;
            int mm = m0 + row; if (mm > nrows - 1) mm = nrows - 1;
            float4 v = *(const float4*)(X + (size_t)mm * NF + k0 + kq * 4);
            sX[(kq * 4 + 0) * 36 + row] = v.x;
            sX[(kq * 4 + 1) * 36 + row] = v.y;
            sX[(kq * 4 + 2) * 36 + row] = v.z;
            sX[(kq * 4 + 3) * 36 + row] = v.w;
        }
#pragma unroll
        for (int j = 0; j < 4; ++j) {    // stage W panels (4 float4 per thread)
            int idx = tid + 256 * j;
            int k = idx >> 5, cq = idx & 31;
            float4 v = *(const float4*)(W + (size_t)(k0 + k) * NF + cq * 4);
            *(float4*)(sW + cq * 132 + k * 4) = v;
        }
        __syncthreads();
#pragma unroll 8
        for (int k = 0; k < TKC; ++k) {
            float4 xf = *(const float4*)(sX + k * 36 + rg * 4);
            float4 wf = *(const float4*)(sW + cg * 132 + k * 4);
            acc[0][0] = fmaf(xf.x, wf.x, acc[0][0]);
            acc[0][1] = fmaf(xf.x, wf.y, acc[0][1]);
            acc[0][2] = fmaf(xf.x, wf.z, acc[0][2]);
            acc[0][3] = fmaf(xf.x, wf.w, acc[0][3]);
            acc[1][0] = fmaf(xf.y, wf.x, acc[1][0]);
            acc[1][1] = fmaf(xf.y, wf.y, acc[1][1]);
            acc[1][2] = fmaf(xf.y, wf.z, acc[1][2]);
            acc[1][3] = fmaf(xf.y, wf.w, acc[1][3]);
            acc[2][0] = fmaf(xf.z, wf.x, acc[2][0]);
            acc[2][1] = fmaf(xf.z, wf.y, acc[2][1]);
            acc[2][2] = fmaf(xf.z, wf.z, acc[2][2]);
            acc[2][3] = fmaf(xf.z, wf.w, acc[2][3]);
            acc[3][0] = fmaf(xf.w, wf.x, acc[3][0]);
            acc[3][1] = fmaf(xf.w, wf.y, acc[3][1]);
            acc[3][2] = fmaf(xf.w, wf.z, acc[3][2]);
            acc[3][3] = fmaf(xf.w, wf.w, acc[3][3]);
        }
        __syncthreads();
    }
#pragma unroll
    for (int r = 0; r < 4; ++r) {
        int m = m0 + rg * 4 + r;
        if (m < nrows) {
            float ds = dinv[m];
            ushort4 h;
            h.x = f2bf(acc[r][0] * ds);
            h.y = f2bf(acc[r][1] * ds);
            h.z = f2bf(acc[r][2] * ds);
            h.w = f2bf(acc[r][3] * ds);
            *(ushort4*)(Y + (size_t)m * NF + cg * 4) = h;
        }
    }
}

// OUT[n] = relu( dinv[n]*( sum_e G[csrc[e]] + G[n] ) + bias ), G bf16.
// One wave per node; half-wave (32 lanes x uint2 = 256B) per edge; 4-deep
// unroll -> 8 independent row reads in flight; fp32 accumulation.
__global__ __launch_bounds__(256) void k_gather(const unsigned short* __restrict__ G,
                                                const int* __restrict__ off,
                                                const int* __restrict__ csrc,
                                                const float* __restrict__ dinv,
                                                const float* __restrict__ bias,
                                                float* __restrict__ OUT) {
    int wid = threadIdx.x >> 6, lane = threadIdx.x & 63;
    int half = lane >> 5;
    int c4 = lane & 31;
    int n = blockIdx.x * 4 + wid;
    if (n >= NN) return;
    int beg = off[n], end = off[n + 1];
    float din = dinv[n];
    float4 acc = make_float4(0.f, 0.f, 0.f, 0.f);
    int e = beg + half;
    for (; e + 6 < end; e += 8) {
        int s0 = csrc[e];
        int s1 = csrc[e + 2];
        int s2 = csrc[e + 4];
        int s3 = csrc[e + 6];
        uint2 p0 = ((const uint2*)(G + (size_t)s0 * NF))[c4];
        uint2 p1 = ((const uint2*)(G + (size_t)s1 * NF))[c4];
        uint2 p2 = ((const uint2*)(G + (size_t)s2 * NF))[c4];
        uint2 p3 = ((const uint2*)(G + (size_t)s3 * NF))[c4];
        acc.x += bf_lo(p0.x); acc.y += bf_hi(p0.x);
        acc.z += bf_lo(p0.y); acc.w += bf_hi(p0.y);
        acc.x += bf_lo(p1.x); acc.y += bf_hi(p1.x);
        acc.z += bf_lo(p1.y); acc.w += bf_hi(p1.y);
        acc.x += bf_lo(p2.x); acc.y += bf_hi(p2.x);
        acc.z += bf_lo(p2.y); acc.w += bf_hi(p2.y);
        acc.x += bf_lo(p3.x); acc.y += bf_hi(p3.x);
        acc.z += bf_lo(p3.y); acc.w += bf_hi(p3.y);
    }
    for (; e < end; e += 2) {
        int s = csrc[e];
        uint2 p = ((const uint2*)(G + (size_t)s * NF))[c4];
        acc.x += bf_lo(p.x); acc.y += bf_hi(p.x);
        acc.z += bf_lo(p.y); acc.w += bf_hi(p.y);
    }
    acc.x += __shfl_xor(acc.x, 32);
    acc.y += __shfl_xor(acc.y, 32);
    acc.z += __shfl_xor(acc.z, 32);
    acc.w += __shfl_xor(acc.w, 32);
    if (half == 0) {
        uint2 sp = ((const uint2*)(G + (size_t)n * NF))[c4];
        float4 bb = ((const float4*)bias)[c4];
        float4 o;
        o.x = fmaxf(fmaf(din, acc.x + bf_lo(sp.x), bb.x), 0.f);
        o.y = fmaxf(fmaf(din, acc.y + bf_hi(sp.x), bb.y), 0.f);
        o.z = fmaxf(fmaf(din, acc.z + bf_lo(sp.y), bb.z), 0.f);
        o.w = fmaxf(fmaf(din, acc.w + bf_hi(sp.y), bb.w), 0.f);
        ((float4*)(OUT + (size_t)n * NF))[c4] = o;
    }
}

// Fused global-mean-pool + final linear (batch is sorted -> contiguous ranges).
__global__ __launch_bounds__(256) void k_poolfin(const float* __restrict__ H,
                                                 const void* __restrict__ batch,
                                                 const float* __restrict__ Wl,
                                                 const float* __restrict__ bl,
                                                 float* __restrict__ out) {
    int is64 = detect64((const int*)batch, NN / 2);
    __shared__ int sb[2];
    __shared__ float4 part[256];
    __shared__ float pooled[NF];
    int g = blockIdx.x;
    int tid = threadIdx.x;
    if (tid < 2) {
        int target = g + tid;                 // lower_bound(batch, target)
        int lo = 0, hi = NN;
        while (lo < hi) {
            int mid = (lo + hi) >> 1;
            if (ld_idx(batch, mid, is64) < target) lo = mid + 1; else hi = mid;
        }
        sb[tid] = lo;
    }
    __syncthreads();
    int beg = sb[0], end = sb[1];
    int c4 = tid & 31, r = tid >> 5;          // 8 rows in flight
    float4 acc = make_float4(0.f, 0.f, 0.f, 0.f);
    for (int n = beg + r; n < end; n += 8) {
        float4 v = ((const float4*)(H + (size_t)n * NF))[c4];
        acc.x += v.x; acc.y += v.y; acc.z += v.z; acc.w += v.w;
    }
    part[tid] = acc;
    __syncthreads();
    if (tid < 32) {
        float4 s = part[tid];
#pragma unroll
        for (int j = 1; j < 8; j++) {
            float4 p = part[tid + 32 * j];
            s.x += p.x; s.y += p.y; s.z += p.z; s.w += p.w;
        }
        float ic = 1.0f / fmaxf((float)(end - beg), 1.0f);
        pooled[tid * 4 + 0] = s.x * ic;
        pooled[tid * 4 + 1] = s.y * ic;
        pooled[tid * 4 + 2] = s.z * ic;
        pooled[tid * 4 + 3] = s.w * ic;
    }
    __syncthreads();
    if (tid < NC) {
        float a = bl[tid];
#pragma unroll 8
        for (int k = 0; k < NF; k++)
            a = fmaf(pooled[k], Wl[k * NC + tid], a);
        out[g * NC + tid] = a;
    }
}

extern "C" void kernel_launch(void* const* d_in, const int* in_sizes, int n_in,
                              void* d_out, int out_size, void* d_ws, size_t ws_size,
                              hipStream_t stream) {
    const float* x  = (const float*)d_in[0];
    const void*  ei = d_in[1];
    const void*  bt = d_in[2];
    const float* W1 = (const float*)d_in[3];
    const float* b1 = (const float*)d_in[4];
    const float* W2 = (const float*)d_in[5];
    const float* b2 = (const float*)d_in[6];
    const float* Wl = (const float*)d_in[7];
    const float* bl = (const float*)d_in[8];

    char* ws = (char*)d_ws;
    int*   coff  = (int*)(ws + 0);
    int*   bbase = (int*)(ws + 40016);
    int*   btot  = (int*)(ws + 41040);
    float* dinv  = (float*)(ws + 42064);
    int*   csrc  = (int*)(ws + 82064);
    unsigned short* Gb = (unsigned short*)(ws + 2642064);  // bf16 G (2.56MB)
    float* bufB  = (float*)(ws + 7762064);                 // f32 H (5.12MB)
    int*   bh    = (int*)(ws + 2642064);   // 512 KB scratch, dead before gemm1
    int*   ebuf  = (int*)(ws + 7762064);   // 2.56 MB scratch, dead before gather1

    k_hist  <<<G1, 256, 0, stream>>>(ei, bh);
    k_bscan1<<<(NB + 3) / 4, 256, 0, stream>>>(bh, btot);
    k_bscan2<<<1, 256, 0, stream>>>(btot, bbase);
    k_bucket<<<G1, 256, 0, stream>>>(ei, bh, bbase, ebuf);
    k_csr   <<<NB, 256, 0, stream>>>(ebuf, bbase, coff, dinv, csrc);

    k_gemm<<<(NN + TM - 1) / TM, 256, 0, stream>>>(x, W1, dinv, Gb, NN);
    k_gather<<<(NN + 3) / 4, 256, 0, stream>>>(Gb, coff, csrc, dinv, b1, bufB);
    k_gemm<<<(NN + TM - 1) / TM, 256, 0, stream>>>(bufB, W2, dinv, Gb, NN);
    k_gather<<<(NN + 3) / 4, 256, 0, stream>>>(Gb, coff, csrc, dinv, b2, bufB);

    k_poolfin<<<NG, 256, 0, stream>>>(bufB, bt, Wl, bl, (float*)d_out);
}

// Round 14
// 166.776 us; speedup vs baseline: 1.5393x; 1.0532x over previous
//
#include <hip/hip_runtime.h>
#include <hip/hip_bf16.h>

#define NN 10000     // nodes
#define NE 640000    // edges
#define NG 64        // graphs
#define NF 128       // feature dim (both layers)
#define NC 10        // classes
#define TM 32        // gemm row tile
#define TKC 32       // gemm k chunk
#define NB 250       // dst buckets (40 nodes each)
#define BSZ 40       // nodes per bucket
#define G1 512       // blocks in hist/bucket passes (2 blocks/CU)
#define ECHUNK 1250  // edges per block (G1*ECHUNK == NE)

// ---------------- ws layout (bytes) ----------------
// 0        coff  (10001 int)        40016
// 40016    bbase (251 int)          1024
// 41040    btot  (250 int)          1024
// 42064    dinv  (10000 f32)        40000
// 82064    csrc  (640000 ushort)    1280000
// 1362064  Gb    (10000*128 bf16)   2560000  [bh (512KB) aliases: dead pre-gemm1]
// 3922064  bufB  (10000*128 f32)    5120000  [ebuf (2.56MB) aliases: dead pre-gath1]
// total ~9.0 MB; zero global atomics -> no pre-zeroing needed
//
// Math: out[i] = relu( dinv[i]*(sum_{j->i} g[j] + g[i]) + b ), g = dinv*h
// folded into the GEMM epilogue. G in bf16 (256B row = 4 lines). R14: gather
// uses quarter-wave (16 lanes x uint4) per edge -> one VMEM instruction
// serves 4 edges/wave (R13 showed per-instruction cost, not lines, binds).

__device__ __forceinline__ unsigned short f2bf(float f) {   // RNE
    unsigned int u = __float_as_uint(f);
    return (unsigned short)((u + 0x7FFF + ((u >> 16) & 1)) >> 16);
}
__device__ __forceinline__ float bf_lo(unsigned int p) {    // low bf16 of pair
    return __uint_as_float(p << 16);
}
__device__ __forceinline__ float bf_hi(unsigned int p) {    // high bf16 of pair
    return __uint_as_float(p & 0xFFFF0000u);
}

// Wave-uniform detection of int64 vs int32 index buffers. For little-endian
// int64, every odd 32-bit word is the (always-zero here) high half.
__device__ __forceinline__ int detect64(const int* w, long span) {
    int lane = threadIdx.x & 63;
    long e = (long)lane * (span - 1) / 63;
    return (__ballot(w[2 * e + 1] != 0) == 0ULL) ? 1 : 0;
}

__device__ __forceinline__ int ld_idx(const void* p, long i, int is64) {
    return is64 ? (int)((const long long*)p)[i] : ((const int*)p)[i];
}

// Pass A: per-block bucket histogram, stored bucket-major: bh[b*G1 + g].
__global__ __launch_bounds__(256) void k_hist(const void* __restrict__ ei,
                                              int* __restrict__ bh) {
    int is64 = detect64((const int*)ei, NE);
    __shared__ int hist[256];
    int tid = threadIdx.x;
    hist[tid] = 0;
    __syncthreads();
    int e0 = blockIdx.x * ECHUNK, e1 = min(NE, e0 + ECHUNK);
    for (int e = e0 + tid; e < e1; e += 256) {
        int dst = ld_idx(ei, (long)NE + e, is64);
        atomicAdd(&hist[dst / BSZ], 1);
    }
    __syncthreads();
    bh[tid * G1 + blockIdx.x] = hist[tid];
}

// Pass B1: per-bucket exclusive prefix over the G1 group counts, parallel
// across 63 blocks (one wave per bucket; 8 vals/lane + shfl wave scan).
__global__ __launch_bounds__(256) void k_bscan1(int* __restrict__ bh,
                                                int* __restrict__ btot) {
    int w = blockIdx.x * 4 + (threadIdx.x >> 6);
    if (w >= NB) return;
    int lane = threadIdx.x & 63;
    int base = w * G1 + lane * 8;
    int vals[8];
    int lsum = 0;
#pragma unroll
    for (int i = 0; i < 8; ++i) { vals[i] = bh[base + i]; lsum += vals[i]; }
    int pref = lsum;
    for (int o = 1; o < 64; o <<= 1) {
        int t = __shfl_up(pref, o, 64);
        if (lane >= o) pref += t;
    }
    int run = pref - lsum;                  // exclusive
#pragma unroll
    for (int i = 0; i < 8; ++i) { int v = vals[i]; bh[base + i] = run; run += v; }
    if (lane == 63) btot[w] = run;
}

// Pass B2: scan 250 bucket totals -> bbase (tiny).
__global__ __launch_bounds__(256) void k_bscan2(const int* __restrict__ btot,
                                                int* __restrict__ bbase) {
    __shared__ int s[256];
    int tid = threadIdx.x;
    s[tid] = (tid < NB) ? btot[tid] : 0;
    __syncthreads();
    if (tid == 0) {
        int run = 0;
        for (int b = 0; b < NB; ++b) { int v = s[b]; s[b] = run; run += v; }
    }
    __syncthreads();
    if (tid < NB) bbase[tid] = s[tid];
    if (tid == 0) bbase[NB] = NE;
}

// Pass C: scatter edges to bucket regions, packed (ldst<<14)|src. Each block
// owns a CONTIGUOUS sub-range per bucket (prefix cursors) -> low write amp.
__global__ __launch_bounds__(256) void k_bucket(const void* __restrict__ ei,
                                                const int* __restrict__ bh,
                                                const int* __restrict__ bbase,
                                                int* __restrict__ ebuf) {
    int is64 = detect64((const int*)ei, NE);
    __shared__ int cur[256];
    int tid = threadIdx.x;
    if (tid < NB) cur[tid] = bh[tid * G1 + blockIdx.x] + bbase[tid];
    __syncthreads();
    int e0 = blockIdx.x * ECHUNK, e1 = min(NE, e0 + ECHUNK);
    for (int e = e0 + tid; e < e1; e += 256) {
        int dst = ld_idx(ei, (long)NE + e, is64);
        int src = ld_idx(ei, (long)e, is64);
        int b = dst / BSZ;
        int p = atomicAdd(&cur[b], 1);
        ebuf[p] = ((dst - b * BSZ) << 14) | src;
    }
}

// Pass D: one block per bucket. Count/scan 40 dsts -> coff + dinv; scatter
// csrc (ushort) within the block-private contiguous region (L2-resident).
__global__ __launch_bounds__(256) void k_csr(const int* __restrict__ ebuf,
                                             const int* __restrict__ bbase,
                                             int* __restrict__ coff,
                                             float* __restrict__ dinv,
                                             unsigned short* __restrict__ csrc) {
    __shared__ int dcount[BSZ];
    __shared__ int dstart[BSZ];
    __shared__ int cur[BSZ];
    int b = blockIdx.x, tid = threadIdx.x;
    if (tid < BSZ) dcount[tid] = 0;
    __syncthreads();
    int base = bbase[b], end = bbase[b + 1];
    for (int i = base + tid; i < end; i += 256)
        atomicAdd(&dcount[ebuf[i] >> 14], 1);
    __syncthreads();
    if (tid == 0) {
        int run = 0;
        for (int i = 0; i < BSZ; ++i) {
            dstart[i] = run; cur[i] = base + run; run += dcount[i];
        }
    }
    __syncthreads();
    if (tid < BSZ) {
        coff[b * BSZ + tid] = base + dstart[tid];
        dinv[b * BSZ + tid] = rsqrtf((float)dcount[tid] + 1.0f);
    }
    if (b == NB - 1 && tid == 0) coff[NN] = NE;
    __syncthreads();
    for (int i = base + tid; i < end; i += 256) {
        int pk = ebuf[i];
        int p = atomicAdd(&cur[pk >> 14], 1);
        csrc[p] = (unsigned short)(pk & 16383);
    }
}

// Y(bf16) = (X @ W) * dinv[row]. Block: 256 thr, 32 rows x 128 cols; 4x4 acc.
// fp32 accumulate; RNE-rounded bf16 store.
__global__ __launch_bounds__(256) void k_gemm(const float* __restrict__ X,
                                              const float* __restrict__ W,
                                              const float* __restrict__ dinv,
                                              unsigned short* __restrict__ Y,
                                              int nrows) {
    __shared__ float sX[TKC * 36];       // 4.6 KB
    __shared__ float sW[32 * 132];       // 16.9 KB
    int tid = threadIdx.x;
    int rg = tid & 7;                    // rows rg*4 .. rg*4+3
    int cg = tid >> 3;                   // cols cg*4 .. cg*4+3 (0..31)
    int m0 = blockIdx.x * TM;
    float acc[4][4] = {{0.f}};
    for (int kc = 0; kc < NF / TKC; ++kc) {
        int k0 = kc * TKC;
        {   // stage X^T (one float4 per thread)
            int row = tid >> 3, kq = tid & 7;
            int mm = m0 + row; if (mm > nrows - 1) mm = nrows - 1;
            float4 v = *(const float4*)(X + (size_t)mm * NF + k0 + kq * 4);
            sX[(kq * 4 + 0) * 36 + row] = v.x;
            sX[(kq * 4 + 1) * 36 + row] = v.y;
            sX[(kq * 4 + 2) * 36 + row] = v.z;
            sX[(kq * 4 + 3) * 36 + row] = v.w;
        }
#pragma unroll
        for (int j = 0; j < 4; ++j) {    // stage W panels (4 float4 per thread)
            int idx = tid + 256 * j;
            int k = idx >> 5, cq = idx & 31;
            float4 v = *(const float4*)(W + (size_t)(k0 + k) * NF + cq * 4);
            *(float4*)(sW + cq * 132 + k * 4) = v;
        }
        __syncthreads();
#pragma unroll 8
        for (int k = 0; k < TKC; ++k) {
            float4 xf = *(const float4*)(sX + k * 36 + rg * 4);
            float4 wf = *(const float4*)(sW + cg * 132 + k * 4);
            acc[0][0] = fmaf(xf.x, wf.x, acc[0][0]);
            acc[0][1] = fmaf(xf.x, wf.y, acc[0][1]);
            acc[0][2] = fmaf(xf.x, wf.z, acc[0][2]);
            acc[0][3] = fmaf(xf.x, wf.w, acc[0][3]);
            acc[1][0] = fmaf(xf.y, wf.x, acc[1][0]);
            acc[1][1] = fmaf(xf.y, wf.y, acc[1][1]);
            acc[1][2] = fmaf(xf.y, wf.z, acc[1][2]);
            acc[1][3] = fmaf(xf.y, wf.w, acc[1][3]);
            acc[2][0] = fmaf(xf.z, wf.x, acc[2][0]);
            acc[2][1] = fmaf(xf.z, wf.y, acc[2][1]);
            acc[2][2] = fmaf(xf.z, wf.z, acc[2][2]);
            acc[2][3] = fmaf(xf.z, wf.w, acc[2][3]);
            acc[3][0] = fmaf(xf.w, wf.x, acc[3][0]);
            acc[3][1] = fmaf(xf.w, wf.y, acc[3][1]);
            acc[3][2] = fmaf(xf.w, wf.z, acc[3][2]);
            acc[3][3] = fmaf(xf.w, wf.w, acc[3][3]);
        }
        __syncthreads();
    }
#pragma unroll
    for (int r = 0; r < 4; ++r) {
        int m = m0 + rg * 4 + r;
        if (m < nrows) {
            float ds = dinv[m];
            ushort4 h;
            h.x = f2bf(acc[r][0] * ds);
            h.y = f2bf(acc[r][1] * ds);
            h.z = f2bf(acc[r][2] * ds);
            h.w = f2bf(acc[r][3] * ds);
            *(ushort4*)(Y + (size_t)m * NF + cg * 4) = h;
        }
    }
}

// OUT[n] = relu( dinv[n]*( sum_e G[csrc[e]] + G[n] ) + bias ), G bf16.
// One wave per node; QUARTER-wave (16 lanes x uint4 = full 256B row) per
// edge -> 4 edges per VMEM instruction; 4-deep unroll -> 16 rows in flight.
// fp32 accumulation (8 features/lane); reduce over quarters via shfl_xor.
__global__ __launch_bounds__(256) void k_gather(const unsigned short* __restrict__ G,
                                                const int* __restrict__ off,
                                                const unsigned short* __restrict__ csrc,
                                                const float* __restrict__ dinv,
                                                const float* __restrict__ bias,
                                                float* __restrict__ OUT) {
    int wid = threadIdx.x >> 6, lane = threadIdx.x & 63;
    int q = lane >> 4, f = lane & 15;
    int n = blockIdx.x * 4 + wid;
    if (n >= NN) return;
    int beg = off[n], end = off[n + 1];
    float din = dinv[n];
    float a0 = 0.f, a1 = 0.f, a2 = 0.f, a3 = 0.f;
    float a4 = 0.f, a5 = 0.f, a6 = 0.f, a7 = 0.f;
    int e = beg + q;
    for (; e + 12 < end; e += 16) {
        int s0 = csrc[e];
        int s1 = csrc[e + 4];
        int s2 = csrc[e + 8];
        int s3 = csrc[e + 12];
        uint4 p0 = ((const uint4*)(G + (size_t)s0 * NF))[f];
        uint4 p1 = ((const uint4*)(G + (size_t)s1 * NF))[f];
        uint4 p2 = ((const uint4*)(G + (size_t)s2 * NF))[f];
        uint4 p3 = ((const uint4*)(G + (size_t)s3 * NF))[f];
        a0 += bf_lo(p0.x); a1 += bf_hi(p0.x); a2 += bf_lo(p0.y); a3 += bf_hi(p0.y);
        a4 += bf_lo(p0.z); a5 += bf_hi(p0.z); a6 += bf_lo(p0.w); a7 += bf_hi(p0.w);
        a0 += bf_lo(p1.x); a1 += bf_hi(p1.x); a2 += bf_lo(p1.y); a3 += bf_hi(p1.y);
        a4 += bf_lo(p1.z); a5 += bf_hi(p1.z); a6 += bf_lo(p1.w); a7 += bf_hi(p1.w);
        a0 += bf_lo(p2.x); a1 += bf_hi(p2.x); a2 += bf_lo(p2.y); a3 += bf_hi(p2.y);
        a4 += bf_lo(p2.z); a5 += bf_hi(p2.z); a6 += bf_lo(p2.w); a7 += bf_hi(p2.w);
        a0 += bf_lo(p3.x); a1 += bf_hi(p3.x); a2 += bf_lo(p3.y); a3 += bf_hi(p3.y);
        a4 += bf_lo(p3.z); a5 += bf_hi(p3.z); a6 += bf_lo(p3.w); a7 += bf_hi(p3.w);
    }
    for (; e < end; e += 4) {
        int s = csrc[e];
        uint4 p = ((const uint4*)(G + (size_t)s * NF))[f];
        a0 += bf_lo(p.x); a1 += bf_hi(p.x); a2 += bf_lo(p.y); a3 += bf_hi(p.y);
        a4 += bf_lo(p.z); a5 += bf_hi(p.z); a6 += bf_lo(p.w); a7 += bf_hi(p.w);
    }
    a0 += __shfl_xor(a0, 16); a1 += __shfl_xor(a1, 16);
    a2 += __shfl_xor(a2, 16); a3 += __shfl_xor(a3, 16);
    a4 += __shfl_xor(a4, 16); a5 += __shfl_xor(a5, 16);
    a6 += __shfl_xor(a6, 16); a7 += __shfl_xor(a7, 16);
    a0 += __shfl_xor(a0, 32); a1 += __shfl_xor(a1, 32);
    a2 += __shfl_xor(a2, 32); a3 += __shfl_xor(a3, 32);
    a4 += __shfl_xor(a4, 32); a5 += __shfl_xor(a5, 32);
    a6 += __shfl_xor(a6, 32); a7 += __shfl_xor(a7, 32);
    if (q == 0) {
        uint4 sp = ((const uint4*)(G + (size_t)n * NF))[f];
        float4 b0 = ((const float4*)bias)[2 * f];
        float4 b1 = ((const float4*)bias)[2 * f + 1];
        float4 o0, o1;
        o0.x = fmaxf(fmaf(din, a0 + bf_lo(sp.x), b0.x), 0.f);
        o0.y = fmaxf(fmaf(din, a1 + bf_hi(sp.x), b0.y), 0.f);
        o0.z = fmaxf(fmaf(din, a2 + bf_lo(sp.y), b0.z), 0.f);
        o0.w = fmaxf(fmaf(din, a3 + bf_hi(sp.y), b0.w), 0.f);
        o1.x = fmaxf(fmaf(din, a4 + bf_lo(sp.z), b1.x), 0.f);
        o1.y = fmaxf(fmaf(din, a5 + bf_hi(sp.z), b1.y), 0.f);
        o1.z = fmaxf(fmaf(din, a6 + bf_lo(sp.w), b1.z), 0.f);
        o1.w = fmaxf(fmaf(din, a7 + bf_hi(sp.w), b1.w), 0.f);
        ((float4*)(OUT + (size_t)n * NF))[2 * f] = o0;
        ((float4*)(OUT + (size_t)n * NF))[2 * f + 1] = o1;
    }
}

// Fused global-mean-pool + final linear (batch is sorted -> contiguous ranges).
__global__ __launch_bounds__(256) void k_poolfin(const float* __restrict__ H,
                                                 const void* __restrict__ batch,
                                                 const float* __restrict__ Wl,
                                                 const float* __restrict__ bl,
                                                 float* __restrict__ out) {
    int is64 = detect64((const int*)batch, NN / 2);
    __shared__ int sb[2];
    __shared__ float4 part[256];
    __shared__ float pooled[NF];
    int g = blockIdx.x;
    int tid = threadIdx.x;
    if (tid < 2) {
        int target = g + tid;                 // lower_bound(batch, target)
        int lo = 0, hi = NN;
        while (lo < hi) {
            int mid = (lo + hi) >> 1;
            if (ld_idx(batch, mid, is64) < target) lo = mid + 1; else hi = mid;
        }
        sb[tid] = lo;
    }
    __syncthreads();
    int beg = sb[0], end = sb[1];
    int c4 = tid & 31, r = tid >> 5;          // 8 rows in flight
    float4 acc = make_float4(0.f, 0.f, 0.f, 0.f);
    for (int n = beg + r; n < end; n += 8) {
        float4 v = ((const float4*)(H + (size_t)n * NF))[c4];
        acc.x += v.x; acc.y += v.y; acc.z += v.z; acc.w += v.w;
    }
    part[tid] = acc;
    __syncthreads();
    if (tid < 32) {
        float4 s = part[tid];
#pragma unroll
        for (int j = 1; j < 8; j++) {
            float4 p = part[tid + 32 * j];
            s.x += p.x; s.y += p.y; s.z += p.z; s.w += p.w;
        }
        float ic = 1.0f / fmaxf((float)(end - beg), 1.0f);
        pooled[tid * 4 + 0] = s.x * ic;
        pooled[tid * 4 + 1] = s.y * ic;
        pooled[tid * 4 + 2] = s.z * ic;
        pooled[tid * 4 + 3] = s.w * ic;
    }
    __syncthreads();
    if (tid < NC) {
        float a = bl[tid];
#pragma unroll 8
        for (int k = 0; k < NF; k++)
            a = fmaf(pooled[k], Wl[k * NC + tid], a);
        out[g * NC + tid] = a;
    }
}

extern "C" void kernel_launch(void* const* d_in, const int* in_sizes, int n_in,
                              void* d_out, int out_size, void* d_ws, size_t ws_size,
                              hipStream_t stream) {
    const float* x  = (const float*)d_in[0];
    const void*  ei = d_in[1];
    const void*  bt = d_in[2];
    const float* W1 = (const float*)d_in[3];
    const float* b1 = (const float*)d_in[4];
    const float* W2 = (const float*)d_in[5];
    const float* b2 = (const float*)d_in[6];
    const float* Wl = (const float*)d_in[7];
    const float* bl = (const float*)d_in[8];

    char* ws = (char*)d_ws;
    int*            coff  = (int*)(ws + 0);
    int*            bbase = (int*)(ws + 40016);
    int*            btot  = (int*)(ws + 41040);
    float*          dinv  = (float*)(ws + 42064);
    unsigned short* csrc  = (unsigned short*)(ws + 82064);
    unsigned short* Gb    = (unsigned short*)(ws + 1362064); // bf16 G (2.56MB)
    float*          bufB  = (float*)(ws + 3922064);          // f32 H (5.12MB)
    int*            bh    = (int*)(ws + 1362064);  // 512KB scratch, dead pre-gemm1
    int*            ebuf  = (int*)(ws + 3922064);  // 2.56MB scratch, dead pre-gather1

    k_hist  <<<G1, 256, 0, stream>>>(ei, bh);
    k_bscan1<<<(NB + 3) / 4, 256, 0, stream>>>(bh, btot);
    k_bscan2<<<1, 256, 0, stream>>>(btot, bbase);
    k_bucket<<<G1, 256, 0, stream>>>(ei, bh, bbase, ebuf);
    k_csr   <<<NB, 256, 0, stream>>>(ebuf, bbase, coff, dinv, csrc);

    k_gemm<<<(NN + TM - 1) / TM, 256, 0, stream>>>(x, W1, dinv, Gb, NN);
    k_gather<<<(NN + 3) / 4, 256, 0, stream>>>(Gb, coff, csrc, dinv, b1, bufB);
    k_gemm<<<(NN + TM - 1) / TM, 256, 0, stream>>>(bufB, W2, dinv, Gb, NN);
    k_gather<<<(NN + 3) / 4, 256, 0, stream>>>(Gb, coff, csrc, dinv, b2, bufB);

    k_poolfin<<<NG, 256, 0, stream>>>(bufB, bt, Wl, bl, (float*)d_out);
}

// Round 15
// 163.752 us; speedup vs baseline: 1.5677x; 1.0185x over previous
//
#include <hip/hip_runtime.h>
#include <hip/hip_bf16.h>

#define NN 10000     // nodes
#define NE 640000    // edges
#define NG 64        // graphs
#define NF 128       // feature dim (both layers)
#define NC 10        // classes
#define TMR 16       // gemm row tile (625 blocks -> 2.4/CU; R14's 32 gave 1.2)
#define TKC 32       // gemm k chunk
#define NB 250       // dst buckets (40 nodes each)
#define BSZ 40       // nodes per bucket
#define G1 512       // blocks in hist/bucket passes (2 blocks/CU)
#define ECHUNK 1250  // edges per block (G1*ECHUNK == NE)

// ---------------- ws layout (bytes) ----------------
// 0        coff  (10001 int)        40016
// 40016    btot  (250 int)          1024
// 41040    dinv  (10000 f32)        40000
// 81040    csrc  (640000 ushort)    1280000
// 1361040  Gb    (10000*128 bf16)   2560000  [bh (512KB) aliases: dead pre-gemm1]
// 3921040  bufB  (10000*128 f32)    5120000  [ebuf (2.56MB) aliases: dead pre-gath1]
// total ~9.0 MB; zero global atomics -> no pre-zeroing needed
//
// Math: out[i] = relu( dinv[i]*(sum_{j->i} g[j] + g[i]) + b ), g = dinv*h
// folded into the GEMM epilogue. G bf16 (256B row). bbase is recomputed
// in-block from btot (2-level shfl scan) -- no bscan2 kernel.

__device__ __forceinline__ unsigned short f2bf(float f) {   // RNE
    unsigned int u = __float_as_uint(f);
    return (unsigned short)((u + 0x7FFF + ((u >> 16) & 1)) >> 16);
}
__device__ __forceinline__ float bf_lo(unsigned int p) {
    return __uint_as_float(p << 16);
}
__device__ __forceinline__ float bf_hi(unsigned int p) {
    return __uint_as_float(p & 0xFFFF0000u);
}

// In-block exclusive scan of btot[0..NB) over 256 threads -> bbs[] (LDS).
// Also leaves vv[] = btot values. ~40 cyc (shfl scan + 4-wave combine).
__device__ __forceinline__ void scan_btot(const int* __restrict__ btot,
                                          int* bbs, int* vv, int* wsum) {
    int tid = threadIdx.x, lane = tid & 63, wv = tid >> 6;
    int v = (tid < NB) ? btot[tid] : 0;
    vv[tid] = v;
    int p = v;
    for (int o = 1; o < 64; o <<= 1) {
        int t = __shfl_up(p, o, 64);
        if (lane >= o) p += t;
    }
    if (lane == 63) wsum[wv] = p;
    __syncthreads();
    int off = 0;
#pragma unroll
    for (int j = 0; j < 4; ++j) if (j < wv) off += wsum[j];
    bbs[tid] = p + off - v;              // exclusive prefix
    __syncthreads();
}

// Wave-uniform detection of int64 vs int32 index buffers. For little-endian
// int64, every odd 32-bit word is the (always-zero here) high half.
__device__ __forceinline__ int detect64(const int* w, long span) {
    int lane = threadIdx.x & 63;
    long e = (long)lane * (span - 1) / 63;
    return (__ballot(w[2 * e + 1] != 0) == 0ULL) ? 1 : 0;
}

__device__ __forceinline__ int ld_idx(const void* p, long i, int is64) {
    return is64 ? (int)((const long long*)p)[i] : ((const int*)p)[i];
}

// Pass A: per-block bucket histogram, stored bucket-major: bh[b*G1 + g].
__global__ __launch_bounds__(256) void k_hist(const void* __restrict__ ei,
                                              int* __restrict__ bh) {
    int is64 = detect64((const int*)ei, NE);
    __shared__ int hist[256];
    int tid = threadIdx.x;
    hist[tid] = 0;
    __syncthreads();
    int e0 = blockIdx.x * ECHUNK, e1 = min(NE, e0 + ECHUNK);
    for (int e = e0 + tid; e < e1; e += 256) {
        int dst = ld_idx(ei, (long)NE + e, is64);
        atomicAdd(&hist[dst / BSZ], 1);
    }
    __syncthreads();
    bh[tid * G1 + blockIdx.x] = hist[tid];
}

// Pass B: per-bucket exclusive prefix over the G1 group counts, parallel
// across 63 blocks (one wave per bucket; 8 vals/lane + shfl wave scan).
__global__ __launch_bounds__(256) void k_bscan1(int* __restrict__ bh,
                                                int* __restrict__ btot) {
    int w = blockIdx.x * 4 + (threadIdx.x >> 6);
    if (w >= NB) return;
    int lane = threadIdx.x & 63;
    int base = w * G1 + lane * 8;
    int vals[8];
    int lsum = 0;
#pragma unroll
    for (int i = 0; i < 8; ++i) { vals[i] = bh[base + i]; lsum += vals[i]; }
    int pref = lsum;
    for (int o = 1; o < 64; o <<= 1) {
        int t = __shfl_up(pref, o, 64);
        if (lane >= o) pref += t;
    }
    int run = pref - lsum;                  // exclusive
#pragma unroll
    for (int i = 0; i < 8; ++i) { int v = vals[i]; bh[base + i] = run; run += v; }
    if (lane == 63) btot[w] = run;
}

// Pass C: scatter edges to bucket regions, packed (ldst<<14)|src. Bucket
// bases recomputed in-block from btot; per-(block,bucket) contiguous ranges.
__global__ __launch_bounds__(256) void k_bucket(const void* __restrict__ ei,
                                                const int* __restrict__ bh,
                                                const int* __restrict__ btot,
                                                int* __restrict__ ebuf) {
    int is64 = detect64((const int*)ei, NE);
    __shared__ int bbs[256], vv[256], wsum[4];
    __shared__ int cur[256];
    int tid = threadIdx.x;
    scan_btot(btot, bbs, vv, wsum);
    if (tid < NB) cur[tid] = bh[tid * G1 + blockIdx.x] + bbs[tid];
    __syncthreads();
    int e0 = blockIdx.x * ECHUNK, e1 = min(NE, e0 + ECHUNK);
    for (int e = e0 + tid; e < e1; e += 256) {
        int dst = ld_idx(ei, (long)NE + e, is64);
        int src = ld_idx(ei, (long)e, is64);
        int b = dst / BSZ;
        int p = atomicAdd(&cur[b], 1);
        ebuf[p] = ((dst - b * BSZ) << 14) | src;
    }
}

// Pass D: one block per bucket. Count/scan 40 dsts -> coff + dinv; scatter
// csrc (ushort) within the block-private contiguous region.
__global__ __launch_bounds__(256) void k_csr(const int* __restrict__ ebuf,
                                             const int* __restrict__ btot,
                                             int* __restrict__ coff,
                                             float* __restrict__ dinv,
                                             unsigned short* __restrict__ csrc) {
    __shared__ int bbs[256], vv[256], wsum[4];
    __shared__ int dcount[BSZ];
    __shared__ int dstart[BSZ];
    __shared__ int cur[BSZ];
    int b = blockIdx.x, tid = threadIdx.x;
    scan_btot(btot, bbs, vv, wsum);
    int base = bbs[b], end = base + vv[b];
    if (tid < BSZ) dcount[tid] = 0;
    __syncthreads();
    for (int i = base + tid; i < end; i += 256)
        atomicAdd(&dcount[ebuf[i] >> 14], 1);
    __syncthreads();
    if (tid == 0) {
        int run = 0;
        for (int i = 0; i < BSZ; ++i) {
            dstart[i] = run; cur[i] = base + run; run += dcount[i];
        }
    }
    __syncthreads();
    if (tid < BSZ) {
        coff[b * BSZ + tid] = base + dstart[tid];
        dinv[b * BSZ + tid] = rsqrtf((float)dcount[tid] + 1.0f);
    }
    if (b == NB - 1 && tid == 0) coff[NN] = NE;
    __syncthreads();
    for (int i = base + tid; i < end; i += 256) {
        int pk = ebuf[i];
        int p = atomicAdd(&cur[pk >> 14], 1);
        csrc[p] = (unsigned short)(pk & 16383);
    }
}

// Y(bf16) = (X @ W) * dinv[row]. 625 blocks x (16 rows x 128 cols), 256 thr;
// per-thread 2 rows x 4 cols. Same kc/k accumulation order as R14 ->
// bit-identical results; smaller tile fixes the 1.2-blocks/CU starvation.
__global__ __launch_bounds__(256) void k_gemm(const float* __restrict__ X,
                                              const float* __restrict__ W,
                                              const float* __restrict__ dinv,
                                              unsigned short* __restrict__ Y,
                                              int nrows) {
    __shared__ float sX[TKC * 20];       // [k][m] stride 20, 2.6 KB
    __shared__ float sW[32 * 132];       // 16.9 KB, 32 col-panels of 4
    int tid = threadIdx.x;
    int rg = tid & 7;                    // rows rg*2, rg*2+1
    int cg = tid >> 3;                   // cols cg*4 .. cg*4+3 (0..31)
    int m0 = blockIdx.x * TMR;
    float acc[2][4] = {{0.f}};
    for (int kc = 0; kc < NF / TKC; ++kc) {
        int k0 = kc * TKC;
        if (tid < 128) {                 // stage X^T (16 rows x 32 k)
            int row = tid >> 3, kq = tid & 7;
            int mm = m0 + row; if (mm > nrows - 1) mm = nrows - 1;
            float4 v = *(const float4*)(X + (size_t)mm * NF + k0 + kq * 4);
            sX[(kq * 4 + 0) * 20 + row] = v.x;
            sX[(kq * 4 + 1) * 20 + row] = v.y;
            sX[(kq * 4 + 2) * 20 + row] = v.z;
            sX[(kq * 4 + 3) * 20 + row] = v.w;
        }
#pragma unroll
        for (int j = 0; j < 4; ++j) {    // stage W panels (4 float4 per thread)
            int idx = tid + 256 * j;
            int k = idx >> 5, cq = idx & 31;
            float4 v = *(const float4*)(W + (size_t)(k0 + k) * NF + cq * 4);
            *(float4*)(sW + cq * 132 + k * 4) = v;
        }
        __syncthreads();
#pragma unroll 8
        for (int k = 0; k < TKC; ++k) {
            float2 xf = *(const float2*)(sX + k * 20 + rg * 2);
            float4 wf = *(const float4*)(sW + cg * 132 + k * 4);
            acc[0][0] = fmaf(xf.x, wf.x, acc[0][0]);
            acc[0][1] = fmaf(xf.x, wf.y, acc[0][1]);
            acc[0][2] = fmaf(xf.x, wf.z, acc[0][2]);
            acc[0][3] = fmaf(xf.x, wf.w, acc[0][3]);
            acc[1][0] = fmaf(xf.y, wf.x, acc[1][0]);
            acc[1][1] = fmaf(xf.y, wf.y, acc[1][1]);
            acc[1][2] = fmaf(xf.y, wf.z, acc[1][2]);
            acc[1][3] = fmaf(xf.y, wf.w, acc[1][3]);
        }
        __syncthreads();
    }
#pragma unroll
    for (int r = 0; r < 2; ++r) {
        int m = m0 + rg * 2 + r;
        if (m < nrows) {
            float ds = dinv[m];
            ushort4 h;
            h.x = f2bf(acc[r][0] * ds);
            h.y = f2bf(acc[r][1] * ds);
            h.z = f2bf(acc[r][2] * ds);
            h.w = f2bf(acc[r][3] * ds);
            *(ushort4*)(Y + (size_t)m * NF + cg * 4) = h;
        }
    }
}

// OUT[n] = relu( dinv[n]*( sum_e G[csrc[e]] + G[n] ) + bias ), G bf16.
// One wave per node; quarter-wave (16 lanes x uint4 = full 256B row) per
// edge -> 4 edges per VMEM instruction; 4-deep unroll; fp32 accumulation.
__global__ __launch_bounds__(256) void k_gather(const unsigned short* __restrict__ G,
                                                const int* __restrict__ off,
                                                const unsigned short* __restrict__ csrc,
                                                const float* __restrict__ dinv,
                                                const float* __restrict__ bias,
                                                float* __restrict__ OUT) {
    int wid = threadIdx.x >> 6, lane = threadIdx.x & 63;
    int q = lane >> 4, f = lane & 15;
    int n = blockIdx.x * 4 + wid;
    if (n >= NN) return;
    int beg = off[n], end = off[n + 1];
    float din = dinv[n];
    float a0 = 0.f, a1 = 0.f, a2 = 0.f, a3 = 0.f;
    float a4 = 0.f, a5 = 0.f, a6 = 0.f, a7 = 0.f;
    int e = beg + q;
    for (; e + 12 < end; e += 16) {
        int s0 = csrc[e];
        int s1 = csrc[e + 4];
        int s2 = csrc[e + 8];
        int s3 = csrc[e + 12];
        uint4 p0 = ((const uint4*)(G + (size_t)s0 * NF))[f];
        uint4 p1 = ((const uint4*)(G + (size_t)s1 * NF))[f];
        uint4 p2 = ((const uint4*)(G + (size_t)s2 * NF))[f];
        uint4 p3 = ((const uint4*)(G + (size_t)s3 * NF))[f];
        a0 += bf_lo(p0.x); a1 += bf_hi(p0.x); a2 += bf_lo(p0.y); a3 += bf_hi(p0.y);
        a4 += bf_lo(p0.z); a5 += bf_hi(p0.z); a6 += bf_lo(p0.w); a7 += bf_hi(p0.w);
        a0 += bf_lo(p1.x); a1 += bf_hi(p1.x); a2 += bf_lo(p1.y); a3 += bf_hi(p1.y);
        a4 += bf_lo(p1.z); a5 += bf_hi(p1.z); a6 += bf_lo(p1.w); a7 += bf_hi(p1.w);
        a0 += bf_lo(p2.x); a1 += bf_hi(p2.x); a2 += bf_lo(p2.y); a3 += bf_hi(p2.y);
        a4 += bf_lo(p2.z); a5 += bf_hi(p2.z); a6 += bf_lo(p2.w); a7 += bf_hi(p2.w);
        a0 += bf_lo(p3.x); a1 += bf_hi(p3.x); a2 += bf_lo(p3.y); a3 += bf_hi(p3.y);
        a4 += bf_lo(p3.z); a5 += bf_hi(p3.z); a6 += bf_lo(p3.w); a7 += bf_hi(p3.w);
    }
    for (; e < end; e += 4) {
        int s = csrc[e];
        uint4 p = ((const uint4*)(G + (size_t)s * NF))[f];
        a0 += bf_lo(p.x); a1 += bf_hi(p.x); a2 += bf_lo(p.y); a3 += bf_hi(p.y);
        a4 += bf_lo(p.z); a5 += bf_hi(p.z); a6 += bf_lo(p.w); a7 += bf_hi(p.w);
    }
    a0 += __shfl_xor(a0, 16); a1 += __shfl_xor(a1, 16);
    a2 += __shfl_xor(a2, 16); a3 += __shfl_xor(a3, 16);
    a4 += __shfl_xor(a4, 16); a5 += __shfl_xor(a5, 16);
    a6 += __shfl_xor(a6, 16); a7 += __shfl_xor(a7, 16);
    a0 += __shfl_xor(a0, 32); a1 += __shfl_xor(a1, 32);
    a2 += __shfl_xor(a2, 32); a3 += __shfl_xor(a3, 32);
    a4 += __shfl_xor(a4, 32); a5 += __shfl_xor(a5, 32);
    a6 += __shfl_xor(a6, 32); a7 += __shfl_xor(a7, 32);
    if (q == 0) {
        uint4 sp = ((const uint4*)(G + (size_t)n * NF))[f];
        float4 b0 = ((const float4*)bias)[2 * f];
        float4 b1 = ((const float4*)bias)[2 * f + 1];
        float4 o0, o1;
        o0.x = fmaxf(fmaf(din, a0 + bf_lo(sp.x), b0.x), 0.f);
        o0.y = fmaxf(fmaf(din, a1 + bf_hi(sp.x), b0.y), 0.f);
        o0.z = fmaxf(fmaf(din, a2 + bf_lo(sp.y), b0.z), 0.f);
        o0.w = fmaxf(fmaf(din, a3 + bf_hi(sp.y), b0.w), 0.f);
        o1.x = fmaxf(fmaf(din, a4 + bf_lo(sp.z), b1.x), 0.f);
        o1.y = fmaxf(fmaf(din, a5 + bf_hi(sp.z), b1.y), 0.f);
        o1.z = fmaxf(fmaf(din, a6 + bf_lo(sp.w), b1.z), 0.f);
        o1.w = fmaxf(fmaf(din, a7 + bf_hi(sp.w), b1.w), 0.f);
        ((float4*)(OUT + (size_t)n * NF))[2 * f] = o0;
        ((float4*)(OUT + (size_t)n * NF))[2 * f + 1] = o1;
    }
}

// Fused global-mean-pool + final linear (batch is sorted -> contiguous ranges).
__global__ __launch_bounds__(256) void k_poolfin(const float* __restrict__ H,
                                                 const void* __restrict__ batch,
                                                 const float* __restrict__ Wl,
                                                 const float* __restrict__ bl,
                                                 float* __restrict__ out) {
    int is64 = detect64((const int*)batch, NN / 2);
    __shared__ int sb[2];
    __shared__ float4 part[256];
    __shared__ float pooled[NF];
    int g = blockIdx.x;
    int tid = threadIdx.x;
    if (tid < 2) {
        int target = g + tid;                 // lower_bound(batch, target)
        int lo = 0, hi = NN;
        while (lo < hi) {
            int mid = (lo + hi) >> 1;
            if (ld_idx(batch, mid, is64) < target) lo = mid + 1; else hi = mid;
        }
        sb[tid] = lo;
    }
    __syncthreads();
    int beg = sb[0], end = sb[1];
    int c4 = tid & 31, r = tid >> 5;          // 8 rows in flight
    float4 acc = make_float4(0.f, 0.f, 0.f, 0.f);
    for (int n = beg + r; n < end; n += 8) {
        float4 v = ((const float4*)(H + (size_t)n * NF))[c4];
        acc.x += v.x; acc.y += v.y; acc.z += v.z; acc.w += v.w;
    }
    part[tid] = acc;
    __syncthreads();
    if (tid < 32) {
        float4 s = part[tid];
#pragma unroll
        for (int j = 1; j < 8; j++) {
            float4 p = part[tid + 32 * j];
            s.x += p.x; s.y += p.y; s.z += p.z; s.w += p.w;
        }
        float ic = 1.0f / fmaxf((float)(end - beg), 1.0f);
        pooled[tid * 4 + 0] = s.x * ic;
        pooled[tid * 4 + 1] = s.y * ic;
        pooled[tid * 4 + 2] = s.z * ic;
        pooled[tid * 4 + 3] = s.w * ic;
    }
    __syncthreads();
    if (tid < NC) {
        float a = bl[tid];
#pragma unroll 8
        for (int k = 0; k < NF; k++)
            a = fmaf(pooled[k], Wl[k * NC + tid], a);
        out[g * NC + tid] = a;
    }
}

extern "C" void kernel_launch(void* const* d_in, const int* in_sizes, int n_in,
                              void* d_out, int out_size, void* d_ws, size_t ws_size,
                              hipStream_t stream) {
    const float* x  = (const float*)d_in[0];
    const void*  ei = d_in[1];
    const void*  bt = d_in[2];
    const float* W1 = (const float*)d_in[3];
    const float* b1 = (const float*)d_in[4];
    const float* W2 = (const float*)d_in[5];
    const float* b2 = (const float*)d_in[6];
    const float* Wl = (const float*)d_in[7];
    const float* bl = (const float*)d_in[8];

    char* ws = (char*)d_ws;
    int*            coff  = (int*)(ws + 0);
    int*            btot  = (int*)(ws + 40016);
    float*          dinv  = (float*)(ws + 41040);
    unsigned short* csrc  = (unsigned short*)(ws + 81040);
    unsigned short* Gb    = (unsigned short*)(ws + 1361040); // bf16 G (2.56MB)
    float*          bufB  = (float*)(ws + 3921040);          // f32 H (5.12MB)
    int*            bh    = (int*)(ws + 1361040);  // 512KB scratch, dead pre-gemm1
    int*            ebuf  = (int*)(ws + 3921040);  // 2.56MB scratch, dead pre-gather1

    k_hist  <<<G1, 256, 0, stream>>>(ei, bh);
    k_bscan1<<<(NB + 3) / 4, 256, 0, stream>>>(bh, btot);
    k_bucket<<<G1, 256, 0, stream>>>(ei, bh, btot, ebuf);
    k_csr   <<<NB, 256, 0, stream>>>(ebuf, btot, coff, dinv, csrc);

    k_gemm<<<(NN + TMR - 1) / TMR, 256, 0, stream>>>(x, W1, dinv, Gb, NN);
    k_gather<<<(NN + 3) / 4, 256, 0, stream>>>(Gb, coff, csrc, dinv, b1, bufB);
    k_gemm<<<(NN + TMR - 1) / TMR, 256, 0, stream>>>(bufB, W2, dinv, Gb, NN);
    k_gather<<<(NN + 3) / 4, 256, 0, stream>>>(Gb, coff, csrc, dinv, b2, bufB);

    k_poolfin<<<NG, 256, 0, stream>>>(bufB, bt, Wl, bl, (float*)d_out);
}